// Round 5
// baseline (1003.143 us; speedup 1.0000x reference)
//
#include <hip/hip_runtime.h>
#include <stdint.h>

#define R_NODES 256
#define M_SAMP  512
#define S_STEPS 512
#define OUT_N   10

typedef uint32_t u32x4 __attribute__((ext_vector_type(4)));

// ---------------- layout detection for bool inputs ----------------
// If bools were uploaded as int32, byte (4f+1) of every element is 0.
// If uploaded as uint8, ~half those bytes are 1.  flag=1 => uint8 layout.
__global__ void detect_layout(const uint8_t* __restrict__ x, int* __restrict__ flag) {
    __shared__ int any;
    if (threadIdx.x == 0) any = 0;
    __syncthreads();
    int acc = 0;
    for (int i = 0; i < 64; ++i)
        acc |= x[(size_t)(threadIdx.x * 64 + i) * 4 + 1];
    if (acc) atomicOr(&any, 1);
    __syncthreads();
    if (threadIdx.x == 0) *flag = any ? 1 : 0;
}

// ---------------- pack x bits: one uint32 per (m,s) ----------------
__global__ void pack_x(const uint8_t* __restrict__ x, const int* __restrict__ flag,
                       uint32_t* __restrict__ xp) {
    const int stride = (*flag) ? 1 : 4;
    const int f = blockIdx.x * blockDim.x + threadIdx.x;      // element idx, M*S*32 total
    const int val = x[(size_t)f * stride];
    const uint64_t mask = __ballot(val != 0);
    const int lane = threadIdx.x & 63;
    if ((lane & 31) == 0) {
        uint32_t w = (lane & 32) ? (uint32_t)(mask >> 32) : (uint32_t)mask;
        xp[f >> 5] = w;
    }
}

// ---------------- build byte-chunk partial-sum table ----------------
// Layout [v][c][j]: T2[(v*32 + c)*256 + j] = sum_{b in v} primes[c*8+b]*W_res[j][c*8+b]
// (uint16, per-chunk max ~12.9K). 4 MB total; ~94% L2-hit in steady state.
__global__ void build_T2(const uint8_t* __restrict__ wres, const int* __restrict__ primes,
                         const int* __restrict__ flag, uint16_t* __restrict__ T2) {
    const int v = blockIdx.x;          // 0..255 byte value
    const int c = blockIdx.y;          // 0..31 chunk
    const int j = threadIdx.x;         // 0..255 node
    const int stride = (*flag) ? 1 : 4;
    int sum = 0;
#pragma unroll
    for (int b = 0; b < 8; ++b) {
        if ((v >> b) & 1) {
            const int k = c * 8 + b;
            if (wres[(size_t)(j * 256 + k) * stride]) sum += primes[k];
        }
    }
    T2[((size_t)v * 32 + c) * 256 + j] = (uint16_t)sum;
}

// ---------------- bit-pack the LUT: 256MB int32 -> 8MB bits ----------------
// Lane-coalesced int4 loads (2 in flight/iter); 4 ballots per chunk; lanes
// 0..7 assemble 8 output words via bit-spread.
__device__ __forceinline__ uint32_t spread8(uint32_t x) {
    // bit i of low byte -> bit 4*i
    x = (x | (x << 12)) & 0x000F000Fu;
    x = (x | (x << 6))  & 0x03030303u;
    x = (x | (x << 3))  & 0x11111111u;
    return x;
}
__device__ __forceinline__ void pack_chunk(const int4 q, int lane, int chunk,
                                           uint32_t* __restrict__ lp32) {
    const uint64_t b0 = __ballot((q.x & 1) != 0);
    const uint64_t b1 = __ballot((q.y & 1) != 0);
    const uint64_t b2 = __ballot((q.z & 1) != 0);
    const uint64_t b3 = __ballot((q.w & 1) != 0);
    if (lane < 8) {
        const uint32_t B0 = (uint32_t)(b0 >> (8 * lane)) & 0xFF;
        const uint32_t B1 = (uint32_t)(b1 >> (8 * lane)) & 0xFF;
        const uint32_t B2 = (uint32_t)(b2 >> (8 * lane)) & 0xFF;
        const uint32_t B3 = (uint32_t)(b3 >> (8 * lane)) & 0xFF;
        const uint32_t w = spread8(B0) | (spread8(B1) << 1)
                         | (spread8(B2) << 2) | (spread8(B3) << 3);
        lp32[(size_t)chunk * 8 + lane] = w;
    }
}
__global__ void pack_lut(const int* __restrict__ lut, uint32_t* __restrict__ lp32) {
    const int lane = threadIdx.x & 63;
    const int gw = blockIdx.x * (blockDim.x >> 6) + (threadIdx.x >> 6); // global wave id, 2048
    const int4* src = (const int4*)lut;
    for (int it = 0; it < 64; ++it) {
        const int c0 = gw * 128 + it * 2;              // 262144 wave-chunks total
        const int4 q0 = src[(size_t)c0 * 64 + lane];        // both loads issue
        const int4 q1 = src[(size_t)(c0 + 1) * 64 + lane];  // before first use
        pack_chunk(q0, lane, c0, lp32);
        pack_chunk(q1, lane, c0 + 1, lp32);
    }
}

// ---------------- main reservoir scan: one block per sample ----------------
// The 32 (chunk,byte) T2 rows needed each step are BLOCK-UNIFORM, loaded
// cooperatively: thread t = (rg=t>>5, cg=t&31) loads a 4-row x 8-col tile.
// Round-4 lesson: at VGPR=20 the compiler serialized the 4 uint4 loads into
// ~4 latency rounds (~1000 extra cyc/step). Inline asm forces all 4 loads
// in flight with ONE s_waitcnt -> one ~250cyc L2 round.
__global__ __launch_bounds__(256, 2) void reservoir_main(
    const uint32_t* __restrict__ xp, const uint16_t* __restrict__ T2,
    const uint64_t* __restrict__ lp, const int* __restrict__ input_nodes,
    const uint8_t* __restrict__ init_res, const int* __restrict__ flag,
    const float* __restrict__ rW, const float* __restrict__ rb,
    float* __restrict__ out)
{
    const int m = blockIdx.x;
    const int t = threadIdx.x;
    const int wid = t >> 6;
    const int lane = t & 63;
    const int rg = t >> 5;      // row group: chunks rg*4 .. rg*4+3
    const int cg = t & 31;      // col group: cols cg*8 .. cg*8+7
    __shared__ uint64_t lmask[4];
    __shared__ uint16_t part[8][256];   // [row-group][node] packed partial sums
    __shared__ float lout[OUT_N];

    const int stride = (*flag) ? 1 : 4;
    int slot = -1;
#pragma unroll
    for (int i = 0; i < 32; ++i)
        if (input_nodes[i] == t) slot = i;

    int v = init_res[(size_t)t * stride] ? 1 : 0;
    const uint64_t* lrow = lp + (size_t)t * 4096;
    const uint32_t* xrow = xp + m * S_STEPS;

    for (int s = 0; s < S_STEPS; ++s) {
        const uint32_t xw = xrow[s];
        if (slot >= 0) v = (xw >> slot) & 1;
        const uint64_t bal = __ballot(v != 0);
        if (lane == 0) lmask[wid] = bal;
        __syncthreads();                                   // B_top
        // this thread's 4 chunks c0..c0+3 live in mask word rg>>1, half rg&1
        const uint64_t mw = lmask[rg >> 1];
        const uint32_t half = (uint32_t)(mw >> ((rg & 1) * 32));
        const int c0 = rg * 4;
        const uint16_t* a0 = T2 + (size_t)(((int)( half        & 0xFF) * 32 + c0 + 0) * 256) + cg * 8;
        const uint16_t* a1 = T2 + (size_t)(((int)((half >>  8) & 0xFF) * 32 + c0 + 1) * 256) + cg * 8;
        const uint16_t* a2 = T2 + (size_t)(((int)((half >> 16) & 0xFF) * 32 + c0 + 2) * 256) + cg * 8;
        const uint16_t* a3 = T2 + (size_t)(((int)( half >> 24        ) * 32 + c0 + 3) * 256) + cg * 8;
        u32x4 l0, l1, l2, l3;
        asm volatile("global_load_dwordx4 %0, %1, off" : "=v"(l0) : "v"(a0) : "memory");
        asm volatile("global_load_dwordx4 %0, %1, off" : "=v"(l1) : "v"(a1) : "memory");
        asm volatile("global_load_dwordx4 %0, %1, off" : "=v"(l2) : "v"(a2) : "memory");
        asm volatile("global_load_dwordx4 %0, %1, off" : "=v"(l3) : "v"(a3) : "memory");
        asm volatile("s_waitcnt vmcnt(0)" ::: "memory");
        u32x4 sm;   // packed u16x2 adds, fields can't overflow (<= 51808)
        sm.x = l0.x + l1.x + l2.x + l3.x;
        sm.y = l0.y + l1.y + l2.y + l3.y;
        sm.z = l0.z + l1.z + l2.z + l3.z;
        sm.w = l0.w + l1.w + l2.w + l3.w;
        *(u32x4*)&part[rg][cg * 8] = sm;
        __syncthreads();                                   // B_mid
        int idx = 0;
#pragma unroll
        for (int r = 0; r < 8; ++r) idx += part[r][t];
        v = (int)((lrow[idx >> 6] >> (idx & 63)) & 1);
    }

    // readout: out[m][o] = b[o] + sum_j v_j * W[o][j]
    __syncthreads();
    if (t < OUT_N) lout[t] = 0.f;
    __syncthreads();
#pragma unroll
    for (int o = 0; o < OUT_N; ++o) {
        float contrib = v ? rW[o * R_NODES + t] : 0.f;
        for (int off = 32; off > 0; off >>= 1)
            contrib += __shfl_down(contrib, off, 64);
        if (lane == 0) atomicAdd(&lout[o], contrib);
    }
    __syncthreads();
    if (t < OUT_N) out[m * OUT_N + t] = lout[t] + rb[t];
}

extern "C" void kernel_launch(void* const* d_in, const int* in_sizes, int n_in,
                              void* d_out, int out_size, void* d_ws, size_t ws_size,
                              hipStream_t stream) {
    const uint8_t* x        = (const uint8_t*)d_in[0];   // bool [M,S,D,B]
    const int* input_nodes  = (const int*)d_in[1];       // int32 [32]
    const int* lut          = (const int*)d_in[2];       // int32 [256, 2^18]
    const uint8_t* wres     = (const uint8_t*)d_in[3];   // bool [256,256]
    const int* primes       = (const int*)d_in[4];       // int32 [256]
    const uint8_t* init_res = (const uint8_t*)d_in[5];   // bool [256]
    const float* rW         = (const float*)d_in[6];     // f32 [10,256]
    const float* rb         = (const float*)d_in[7];     // f32 [10]
    float* out              = (float*)d_out;             // f32 [512,10]

    uint8_t* ws = (uint8_t*)d_ws;
    int*      flag = (int*)ws;                                        // 4 B
    uint32_t* xp   = (uint32_t*)(ws + 4096);                          // 1 MB
    uint16_t* T2   = (uint16_t*)(ws + 4096 + 1048576);                // 4 MB
    uint64_t* lp   = (uint64_t*)(ws + 4096 + 1048576 + 4194304);      // 8 MB

    detect_layout<<<1, 256, 0, stream>>>(x, flag);
    pack_x<<<(M_SAMP * S_STEPS * 32) / 256, 256, 0, stream>>>(x, flag, xp);
    build_T2<<<dim3(256, 32), 256, 0, stream>>>(wres, primes, flag, T2);
    pack_lut<<<512, 256, 0, stream>>>(lut, (uint32_t*)lp);
    reservoir_main<<<M_SAMP, 256, 0, stream>>>(xp, T2, lp, input_nodes, init_res,
                                               flag, rW, rb, out);
}